// Round 8
// baseline (470.227 us; speedup 1.0000x reference)
//
#include <hip/hip_runtime.h>

#define NINST 100
#define MLOG 28
#define IMG 800
#define LOGSZ (MLOG * MLOG) /* 784 */
#define NBLK2 512           /* k_fused grid; __launch_bounds__(256,2) -> capacity >= 512 co-resident (no deadlock) */
#define PCAP  256
#define PL4   (IMG * IMG / 4) /* 160000 float4 per plane */
#define CH4   (PL4 / 5)       /* 32000 float4 per (slot,chunk) */

// ws layout (32-bit words):
//  [0..99]    order   [100..199] cls   [200..599] box   [600..699] msum
//  [800..899] slot_n  [900] nkeep  [901] npairs  [904..905] barrier counters
//  [1024..1791] pair triplets (i,j,ovl) x PCAP   (written via agent atomics)
//  [11264..]  bit-packed masks, stride 3648 words (12 x 304 rows), word col
//             aligned to GLOBAL word grid (word = x/32) so AND needs no shift.
#define OFF_ORDER 0
#define OFF_CLS   100
#define OFF_BOX   200
#define OFF_MSUM  600
#define OFF_SLOT  800
#define OFF_NK    900
#define OFF_NPAIR 901
#define OFF_BAR   904
#define OFF_PAIRS 1024
#define OFF_MASK  11264
#define ROWW      12
#define MSTRIDE   (ROWW * 304)

#define AGENT __HIP_MEMORY_SCOPE_AGENT

__device__ __forceinline__ bool box_ovl(const int* sb, int a, int b2) {
    int axs = max(sb[4 * a], 0), axe = min(sb[4 * a + 2] + 1, IMG);
    int ays = max(sb[4 * a + 1], 0), aye = min(sb[4 * a + 3] + 1, IMG);
    int bxs = max(sb[4 * b2], 0), bxe = min(sb[4 * b2 + 2] + 1, IMG);
    int bys = max(sb[4 * b2 + 1], 0), bye = min(sb[4 * b2 + 3] + 1, IMG);
    return axs < bxe && bxs < axe && ays < bye && bys < aye;
}

// Device-scope grid barrier. Counter zero-inited by k_mask (kernel-boundary
// coherence). Release on arrive, acquire on spin; control data crossing the
// barrier travels via agent-scope atomics.
__device__ __forceinline__ void gbar(int* cnt, int nblk) {
    __syncthreads();
    if (threadIdx.x == 0) {
        __threadfence();
        __hip_atomic_fetch_add(cnt, 1, __ATOMIC_RELEASE, AGENT);
        while (__hip_atomic_load(cnt, __ATOMIC_ACQUIRE, AGENT) < nblk)
            __builtin_amdgcn_s_sleep(8);
    }
    __syncthreads();
}

// K1, blocks [0,100): rank (redundant, from LDS) + rasterize bit-masks + msum
// + zero-init the control words K2 needs (npair, barrier counters).
__global__ __launch_bounds__(256) void k_mask(const float* __restrict__ mask_prob,
                                              const float* __restrict__ cls_prob,
                                              const float* __restrict__ rois,
                                              const int* __restrict__ cls_idx,
                                              int* __restrict__ ws) {
    int b = blockIdx.x, tid = threadIdx.x;
    __shared__ float s_p[NINST];
    __shared__ int s_order[NINST];
    __shared__ float lg[LOGSZ];
    __shared__ int red[256];
    if (tid < NINST) s_p[tid] = cls_prob[tid];
    __syncthreads();
    if (tid < NINST) {
        float p = s_p[tid];
        int r = 0;
        for (int j = 0; j < NINST; j++) {
            float q = s_p[j];
            r += (q > p) || (q == p && j < tid); // stable argsort(-cls_prob)
        }
        s_order[r] = tid;
    }
    __syncthreads();
    int n = b;
    int orig = s_order[n];
    int x0 = (int)rois[4 * orig], y0 = (int)rois[4 * orig + 1];
    int x1 = (int)rois[4 * orig + 2], y1 = (int)rois[4 * orig + 3];
    if (b == 0) {
        if (tid == 0) {
            ws[OFF_NPAIR] = 0;
            ws[OFF_BAR] = 0;
            ws[OFF_BAR + 1] = 0;
        }
        if (tid < NINST) { // publish metadata
            int o = s_order[tid];
            ws[OFF_ORDER + tid] = o;
            ws[OFF_CLS + tid] = cls_idx[o] - 1;
#pragma unroll
            for (int k = 0; k < 4; k++)
                ws[OFF_BOX + 4 * tid + k] = (int)rois[4 * o + k]; // trunc == astype(int32)
        }
    }
    for (int i = tid; i < LOGSZ; i += 256) lg[i] = mask_prob[orig * LOGSZ + i];
    __syncthreads();
    int xs = max(x0, 0), xe = min(x1 + 1, IMG);
    int ys = max(y0, 0), ye = min(y1 + 1, IMG);
    int wx0 = xs >> 5, nw = ((xe + 31) >> 5) - wx0, nrows = ye - ys;
    float wf = fmaxf((float)(x1 - x0 + 1), 1.f), hf = fmaxf((float)(y1 - y0 + 1), 1.f);
    float rx = 28.f / wf, ry = 28.f / hf;
    unsigned* mb = (unsigned*)(ws + OFF_MASK) + n * MSTRIDE;
    int total = nrows * nw, cnt = 0;
    for (int t = tid; t < total; t += 256) {
        int row = t / nw, wc = t - row * nw;
        int y = ys + row;
        float sy = ((float)y - (float)y0 + 0.5f) * ry - 0.5f;
        sy = fminf(fmaxf(sy, 0.f), 27.f);
        int iy0 = (int)sy, iy1 = min(iy0 + 1, 27);
        float fy = sy - (float)iy0;
        const float* r0 = lg + iy0 * MLOG;
        const float* r1 = lg + iy1 * MLOG;
        unsigned bits = 0u;
        int xbase = (wx0 + wc) << 5;
        int j0 = max(xs - xbase, 0), j1 = min(xe - xbase, 32);
        for (int j = j0; j < j1; j++) {
            int xx = xbase + j;
            float sx = ((float)xx - (float)x0 + 0.5f) * rx - 0.5f;
            sx = fminf(fmaxf(sx, 0.f), 27.f);
            int ix0 = (int)sx, ix1 = min(ix0 + 1, 27);
            float fx = sx - (float)ix0;
            float val = (1.f - fy) * ((1.f - fx) * r0[ix0] + fx * r0[ix1]) +
                        fy * ((1.f - fx) * r1[ix0] + fx * r1[ix1]);
            bits |= (val > 0.f) ? (1u << j) : 0u;
        }
        mb[row * ROWW + wc] = bits;
        cnt += __popc(bits);
    }
    red[tid] = cnt;
    __syncthreads();
    for (int s = 128; s; s >>= 1) {
        if (tid < s) red[tid] += red[tid + s];
        __syncthreads();
    }
    if (tid == 0) ws[OFF_MSUM + n] = red[0];
}

// K2: pairs -> barrier -> scan -> barrier -> fused full-output write.
// 512 blocks, all guaranteed co-resident (see NBLK2 note).
__global__ __launch_bounds__(256, 2) void k_fused(const float* __restrict__ mask_prob,
                                                  int* __restrict__ ws,
                                                  float* __restrict__ out) {
    int b = blockIdx.x, tid = threadIdx.x;
    __shared__ int s_ovl[NINST * NINST]; // 40 KB, block 0 only
    __shared__ int s_cls[NINST], s_msum[NINST], s_box[4 * NINST];
    __shared__ float lg[LOGSZ];
    const unsigned* maskbase = (const unsigned*)(ws + OFF_MASK);

    // ---- Phase P: pair popcounts, one wave per candidate pair ----
    {
        int wid = b * 4 + (tid >> 6), ln = tid & 63;
        for (int p = wid; p < NINST * NINST; p += NBLK2 * 4) {
            int i = p / NINST, j = p - i * NINST;
            if (i >= j) continue;
            if (ws[OFF_CLS + i] != ws[OFF_CLS + j]) continue;
            if (ws[OFF_MSUM + i] == 0 || ws[OFF_MSUM + j] == 0) continue;
            const int* bi = ws + OFF_BOX + 4 * i;
            const int* bj = ws + OFF_BOX + 4 * j;
            int ixs = max(bi[0], 0), ixe = min(bi[2] + 1, IMG);
            int iys = max(bi[1], 0), iye = min(bi[3] + 1, IMG);
            int jxs = max(bj[0], 0), jxe = min(bj[2] + 1, IMG);
            int jys = max(bj[1], 0), jye = min(bj[3] + 1, IMG);
            if (!(ixs < jxe && jxs < ixe && iys < jye && jys < iye)) continue;
            int iwx0 = ixs >> 5, jwx0 = jxs >> 5;
            int wlo = max(iwx0, jwx0);
            int whi = min((ixe + 31) >> 5, (jxe + 31) >> 5);
            int rlo = max(iys, jys), rhi = min(iye, jye);
            int nw = whi - wlo, nrows = rhi - rlo;
            const unsigned* mi = maskbase + i * MSTRIDE;
            const unsigned* mj = maskbase + j * MSTRIDE;
            int total = nrows * nw, cnt = 0;
            for (int t = ln; t < total; t += 64) {
                int row = t / nw, wc = t - row * nw;
                int y = rlo + row, w = wlo + wc;
                cnt += __popc(mi[(y - iys) * ROWW + (w - iwx0)] &
                              mj[(y - jys) * ROWW + (w - jwx0)]);
            }
            for (int off = 32; off; off >>= 1) cnt += __shfl_down(cnt, off);
            if (ln == 0) {
                int k = __hip_atomic_fetch_add(ws + OFF_NPAIR, 1, __ATOMIC_RELAXED, AGENT);
                if (k < PCAP) {
                    __hip_atomic_store(ws + OFF_PAIRS + 3 * k, i, __ATOMIC_RELAXED, AGENT);
                    __hip_atomic_store(ws + OFF_PAIRS + 3 * k + 1, j, __ATOMIC_RELAXED, AGENT);
                    __hip_atomic_store(ws + OFF_PAIRS + 3 * k + 2, cnt, __ATOMIC_RELAXED, AGENT);
                }
            }
        }
    }
    gbar(ws + OFF_BAR, NBLK2);

    // ---- Phase S: block 0 wave scan; others wait at the next barrier ----
    if (b == 0) {
        for (int q = tid; q < NINST * NINST; q += 256) s_ovl[q] = 0;
        for (int q = tid; q < NINST; q += 256) {
            s_cls[q] = ws[OFF_CLS + q];
            s_msum[q] = ws[OFF_MSUM + q];
        }
        for (int q = tid; q < 4 * NINST; q += 256) s_box[q] = ws[OFF_BOX + q];
        int npr = __hip_atomic_load(ws + OFF_NPAIR, __ATOMIC_RELAXED, AGENT);
        int np = min(npr, PCAP);
        bool pov = (npr > PCAP);
        __syncthreads();
        for (int q = tid; q < np; q += 256) {
            int i = __hip_atomic_load(ws + OFF_PAIRS + 3 * q, __ATOMIC_RELAXED, AGENT);
            int j = __hip_atomic_load(ws + OFF_PAIRS + 3 * q + 1, __ATOMIC_RELAXED, AGENT);
            int c = __hip_atomic_load(ws + OFF_PAIRS + 3 * q + 2, __ATOMIC_RELAXED, AGENT);
            s_ovl[i * NINST + j] = c;
        }
        __syncthreads();
        if (tid < 64) { // single wave, no barriers
            int ln = tid;
            unsigned long long k0 = 0ull, k1 = 0ull; // replicated keep masks
            for (int n = 0; n < NINST; n++) {
                int msum = s_msum[n];
                if (msum == 0) continue;
                int pb = 64 + ln;
                bool ca = (ln < n) && s_cls[ln] == s_cls[n] && ((k0 >> ln) & 1ull) && box_ovl(s_box, ln, n);
                bool cb = (pb < n) && s_cls[pb] == s_cls[n] && ((k1 >> ln) & 1ull) && box_ovl(s_box, pb, n);
                int oa = ca ? s_ovl[ln * NINST + n] : 0;
                int ob = cb ? s_ovl[pb * NINST + n] : 0;
                int sum = oa + ob, mx = max(oa, ob);
                for (int off = 32; off; off >>= 1) {
                    sum += __shfl_down(sum, off);
                    mx = max(mx, __shfl_down(mx, off));
                }
                unsigned long long anyc = __ballot(ca || cb);
                int keep = 0, need = 0;
                if (ln == 0) {
                    float t = 0.3f * (float)msum;
                    if (pov) { need = (anyc != 0ull); keep = (!need); }
                    else if ((float)sum <= t) keep = 1;
                    else if ((float)mx > t) keep = 0;
                    else need = 1; // max <= t < sum: exact union required
                }
                keep = __shfl(keep, 0);
                need = __shfl(need, 0);
                if (need) { // wave-cooperative exact union popcount (rare)
                    unsigned long long ba = __ballot(ca), bb = __ballot(cb);
                    int nxs = max(s_box[4 * n], 0), nxe = min(s_box[4 * n + 2] + 1, IMG);
                    int nys = max(s_box[4 * n + 1], 0), nye = min(s_box[4 * n + 3] + 1, IMG);
                    int wx0 = nxs >> 5, nw = ((nxe + 31) >> 5) - wx0, nrows = nye - nys;
                    const unsigned* mn = maskbase + n * MSTRIDE;
                    int total = nrows * nw, ovl = 0;
                    for (int t2 = ln; t2 < total; t2 += 64) {
                        int row = t2 / nw, wc = t2 - row * nw;
                        unsigned bits = mn[row * ROWW + wc];
                        if (!bits) continue;
                        int y = nys + row, wa = wx0 + wc;
                        unsigned img = 0;
                        unsigned long long rem = ba;
                        while (rem) {
                            int m = __ffsll((long long)rem) - 1; rem &= rem - 1;
                            int mys = max(s_box[4 * m + 1], 0), mye = min(s_box[4 * m + 3] + 1, IMG);
                            int mxs = max(s_box[4 * m], 0), mxe = min(s_box[4 * m + 2] + 1, IMG);
                            int mwx0 = mxs >> 5, mnw = ((mxe + 31) >> 5) - mwx0;
                            int rr = y - mys, cc = wa - mwx0;
                            if (rr >= 0 && rr < (mye - mys) && cc >= 0 && cc < mnw)
                                img |= maskbase[m * MSTRIDE + rr * ROWW + cc];
                        }
                        rem = bb;
                        while (rem) {
                            int m0 = __ffsll((long long)rem) - 1; rem &= rem - 1;
                            int m = 64 + m0;
                            int mys = max(s_box[4 * m + 1], 0), mye = min(s_box[4 * m + 3] + 1, IMG);
                            int mxs = max(s_box[4 * m], 0), mxe = min(s_box[4 * m + 2] + 1, IMG);
                            int mwx0 = mxs >> 5, mnw = ((mxe + 31) >> 5) - mwx0;
                            int rr = y - mys, cc = wa - mwx0;
                            if (rr >= 0 && rr < (mye - mys) && cc >= 0 && cc < mnw)
                                img |= maskbase[m * MSTRIDE + rr * ROWW + cc];
                        }
                        ovl += __popc(bits & img);
                    }
                    for (int off = 32; off; off >>= 1) ovl += __shfl_down(ovl, off);
                    if (ln == 0) keep = ((float)ovl <= 0.3f * (float)msum);
                    keep = __shfl(keep, 0);
                }
                if (keep) {
                    if (n < 64) k0 |= 1ull << n;
                    else k1 |= 1ull << (n - 64);
                }
            }
            // epilogue: nk + slots via agent atomics; keep_inds to out
            int nk = __popcll(k0) + __popcll(k1);
            if (ln == 0) __hip_atomic_store(ws + OFF_NK, nk, __ATOMIC_RELAXED, AGENT);
            unsigned long long lm = (ln == 0) ? 0ull : (~0ull >> (64 - ln));
            if ((k0 >> ln) & 1ull) {
                int pos = __popcll(k0 & lm);
                __hip_atomic_store(ws + OFF_SLOT + pos, ln, __ATOMIC_RELAXED, AGENT);
                out[pos] = (float)ws[OFF_ORDER + ln];
            }
            if (ln < 36 && ((k1 >> ln) & 1ull)) {
                int pos = __popcll(k0) + __popcll(k1 & lm);
                __hip_atomic_store(ws + OFF_SLOT + pos, 64 + ln, __ATOMIC_RELAXED, AGENT);
                out[pos] = (float)ws[OFF_ORDER + 64 + ln];
            }
            for (int s = ln; s < NINST; s += 64)
                if (s >= nk) out[s] = -1.f;
        }
        __syncthreads();
    }
    gbar(ws + OFF_BAR + 1, NBLK2);

    // ---- Phase D: fused full-output write, 5 chunk-blocks per plane ----
    if (b >= 5 * NINST) return;
    int slot = b / 5, chunk = b - 5 * slot;
    int nk = __hip_atomic_load(ws + OFF_NK, __ATOMIC_RELAXED, AGENT);
    float4* plane = (float4*)(out + NINST) + (size_t)slot * PL4;
    int base4 = chunk * CH4;
    if (slot >= nk) {
        float4 z = make_float4(0.f, 0.f, 0.f, 0.f);
        for (int i = tid; i < CH4; i += 256) plane[base4 + i] = z;
        return;
    }
    int n = __hip_atomic_load(ws + OFF_SLOT + slot, __ATOMIC_RELAXED, AGENT);
    int orig = ws[OFF_ORDER + n]; // K1 data: coherent via kernel boundary
    const int* box = ws + OFF_BOX + 4 * n;
    int x0 = box[0], y0 = box[1], x1 = box[2], y1 = box[3];
    int xs = max(x0, 0), xe = min(x1 + 1, IMG);
    int ys = max(y0, 0), ye = min(y1 + 1, IMG);
    for (int i = tid; i < LOGSZ; i += 256) lg[i] = mask_prob[orig * LOGSZ + i];
    __syncthreads();
    float wf = fmaxf((float)(x1 - x0 + 1), 1.f), hf = fmaxf((float)(y1 - y0 + 1), 1.f);
    float rx = 28.f / wf, ry = 28.f / hf;
    for (int i = tid; i < CH4; i += 256) {
        int idx4 = base4 + i;
        int y = idx4 / (IMG / 4);          // 200 float4 per row
        int xb = (idx4 - y * (IMG / 4)) * 4;
        float4 res = make_float4(0.f, 0.f, 0.f, 0.f);
        if (y >= ys && y < ye && xb + 3 >= xs && xb < xe) {
            float sy = ((float)y - (float)y0 + 0.5f) * ry - 0.5f;
            sy = fminf(fmaxf(sy, 0.f), 27.f);
            int iy0 = (int)sy, iy1 = min(iy0 + 1, 27);
            float fy = sy - (float)iy0;
            const float* r0 = lg + iy0 * MLOG;
            const float* r1 = lg + iy1 * MLOG;
            float v[4];
#pragma unroll
            for (int j = 0; j < 4; j++) {
                int xx = xb + j;
                float val = 0.f;
                if (xx >= xs && xx < xe) {
                    float sx = ((float)xx - (float)x0 + 0.5f) * rx - 0.5f;
                    sx = fminf(fmaxf(sx, 0.f), 27.f);
                    int ix0 = (int)sx, ix1 = min(ix0 + 1, 27);
                    float fx = sx - (float)ix0;
                    val = (1.f - fy) * ((1.f - fx) * r0[ix0] + fx * r0[ix1]) +
                          fy * ((1.f - fx) * r1[ix0] + fx * r1[ix1]);
                }
                v[j] = val;
            }
            res = make_float4(v[0], v[1], v[2], v[3]);
        }
        plane[idx4] = res;
    }
}

extern "C" void kernel_launch(void* const* d_in, const int* in_sizes, int n_in,
                              void* d_out, int out_size, void* d_ws, size_t ws_size,
                              hipStream_t stream) {
    const float* rois      = (const float*)d_in[0];
    const float* cls_prob  = (const float*)d_in[1];
    const float* mask_prob = (const float*)d_in[2];
    const int*   cls_idx   = (const int*)d_in[3];
    int* ws = (int*)d_ws;
    float* out = (float*)d_out;

    k_mask<<<dim3(NINST), dim3(256), 0, stream>>>(mask_prob, cls_prob, rois, cls_idx, ws);
    k_fused<<<dim3(NBLK2), dim3(256), 0, stream>>>(mask_prob, ws, out);
}